// Round 8
// baseline (552.702 us; speedup 1.0000x reference)
//
#include <hip/hip_runtime.h>

// LSTM autoencoder: 4 layers 64->64, B=512, T=256 — fused, ANTI-PHASED halves.
//
// 256 blocks x 512 threads (1 block/CU). Block = 2 batch elements x 4 layers.
// Wave w = (layer L = w>>1, unit-half mh = w&1). Datapath = fused6 verbatim.
//
// ROUND-6 RESTRUCTURE (measured evidence): fused6's 3220-cy tick is the SUM
// of per-CU MFMA-pipe time (256 MFMA x 4.85 = 1242 cy), VALU/trans time
// (760 cy) and LDS/barrier latency — serialized because all 8 waves are in
// the same phase on every SIMD. Fix: split each step into two half-windows,
//   RM-half: read fragments + 32 MFMA + Gs scatter/gather issue
//   TW-half: gate transcendentals + cst update + h write (+L3 out store)
// and schedule waves 0-3 (L0,L1) OPPOSITE to waves 4-7 (L2,L3). With the
// standard wave->SIMD mapping (w&3), each SIMD gets one wave of each group,
// so one wave's MFMA phase overlaps the other's trans phase.
// Layer L's first RM is at half-window {0,2,5,7}[L]; step t RM at
// rmStart+2t. Dependency check (h ring slot = t&3, 4 slots):
//   L1 reads h_L0(t) at H(2t+2), published end H(2t+1)  [barrier-ordered]
//   L2 reads h_L1(t) at H(2t+5), published end H(2t+3)
//   L3 reads h_L2(t) at H(2t+7), published end H(2t+6)
//   own h(t-1) always published 2 half-windows before use; slot reuse is
//   4 steps = 8 half-windows later — all consumers done. No flags, no polls.
// Barriers: lgkmcnt(0)-only drain (vmcnt stays in flight: x prefetch + out).

typedef _Float16 f16x8 __attribute__((ext_vector_type(8)));
typedef float    f32x4 __attribute__((ext_vector_type(4)));

#define TSEQ 256

__device__ __forceinline__ float fast_rcp(float x) { return __builtin_amdgcn_rcpf(x); }
__device__ __forceinline__ float sigm(float x) { return fast_rcp(1.0f + __expf(-x)); }
__device__ __forceinline__ float tanh_fast(float x) {
    return 2.0f * fast_rcp(1.0f + __expf(-2.0f * x)) - 1.0f;
}
__device__ __forceinline__ f16x8 cvt8(float4 a, float4 b) {
    f16x8 f;
    f[0] = (_Float16)a.x; f[1] = (_Float16)a.y; f[2] = (_Float16)a.z; f[3] = (_Float16)a.w;
    f[4] = (_Float16)b.x; f[5] = (_Float16)b.y; f[6] = (_Float16)b.z; f[7] = (_Float16)b.w;
    return f;
}

__global__ __launch_bounds__(512, 2)
void lstm_fused10(const float* __restrict__ x,     // [512, 256, 64]
                  float* __restrict__ out,         // [512, 256, 64]
                  const float* __restrict__ Wih0, const float* __restrict__ Whh0,
                  const float* __restrict__ bi0,  const float* __restrict__ bh0,
                  const float* __restrict__ Wih1, const float* __restrict__ Whh1,
                  const float* __restrict__ bi1,  const float* __restrict__ bh1,
                  const float* __restrict__ Wih2, const float* __restrict__ Whh2,
                  const float* __restrict__ bi2,  const float* __restrict__ bh2,
                  const float* __restrict__ Wih3, const float* __restrict__ Whh3,
                  const float* __restrict__ bi3,  const float* __restrict__ bh3)
{
    __shared__ float    Gs[8 * 256];         // 8 KB: per-wave gate scratch
    __shared__ _Float16 Hb[4][4][2][64];     // 4 KB: slot ring (t&3), layer, el, unit

    const int tid  = threadIdx.x;
    const int wave = tid >> 6;
    const int lane = tid & 63;
    const int L    = wave >> 1;     // layer 0..3
    const int mh   = wave & 1;      // unit-half: units [mh*32, mh*32+32)
    const int q    = lane >> 4;     // quad
    const int n    = lane & 15;     // MFMA col; valid batch cols are n<2
    const int b0   = blockIdx.x * 2;

    const bool isB     = (L >= 2);                 // anti-phase group
    const int  rmStart = 2 * L + (isB ? 1 : 0);    // first RM half-window: 0,2,5,7

    const float* Wih = (L == 0) ? Wih0 : (L == 1) ? Wih1 : (L == 2) ? Wih2 : Wih3;
    const float* Whh = (L == 0) ? Whh0 : (L == 1) ? Whh1 : (L == 2) ? Whh2 : Whh3;
    const float* bi  = (L == 0) ? bi0  : (L == 1) ? bi1  : (L == 2) ? bi2  : bi3;
    const float* bh  = (L == 0) ? bh0  : (L == 1) ? bh1  : (L == 2) ? bh2  : bh3;

    // ---- persistent A-fragments: tile (g,j) = rows g*64+mh*32+j*16+[0,16) ----
    f16x8 Aih[4][2][2], Ahh[4][2][2];
#pragma unroll
    for (int g = 0; g < 4; ++g) {
#pragma unroll
        for (int j = 0; j < 2; ++j) {
            const int row = g * 64 + mh * 32 + j * 16 + n;
#pragma unroll
            for (int c = 0; c < 2; ++c) {
                const float* pi = Wih + row * 64 + c * 32 + q * 8;
                const float* ph = Whh + row * 64 + c * 32 + q * 8;
                f16x8 fi, fh;
#pragma unroll
                for (int k = 0; k < 8; ++k) { fi[k] = (_Float16)pi[k]; fh[k] = (_Float16)ph[k]; }
                Aih[g][j][c] = fi;
                Ahh[g][j][c] = fh;
            }
        }
    }

    // ---- epilogue identity: lane owns (el = lane>>5, unit = mh*32+(lane&31)) ----
    const int eu = lane & 31;
    const int el = lane >> 5;
    const int unit = mh * 32 + eu;
    float4 be;
    be.x = bi[unit]       + bh[unit];
    be.y = bi[64 + unit]  + bh[64 + unit];
    be.z = bi[128 + unit] + bh[128 + unit];
    be.w = bi[192 + unit] + bh[192 + unit];
    float cst = 0.0f;
    float* outp = out + ((size_t)(b0 + el) * TSEQ) * 64 + unit;   // L==3 only

    // Gs addressing (compile-time-constant per lane)
    const int wo = wave * 256 + n * 128 + q * 4;
    const int ro = wave * 256 + el * 128 + (eu >> 4) * 64 + ((eu >> 2) & 3) * 4 + (eu & 3);

    // ---- zero h ring (all 4 slots): 4096 B = 1024 ints ----
    ((int*)Hb)[tid] = 0;
    ((int*)Hb)[tid + 512] = 0;

    // ---- L0 x prefetch: x(0) (lanes n<2 only; rest zero) ----
    const float* xbase = x + ((size_t)(b0 + (n & 1)) * TSEQ) * 64 + q * 8;
    float4 R0, R1, R2, R3;
    R0 = R1 = R2 = R3 = make_float4(0.f, 0.f, 0.f, 0.f);
    if (L == 0 && n < 2) {
        R0 = *(const float4*)(xbase);      R1 = *(const float4*)(xbase + 4);
        R2 = *(const float4*)(xbase + 32); R3 = *(const float4*)(xbase + 36);
    }

    __syncthreads();   // init visible to all waves

    // carried across the TW half-window
    float gvx = 0.f, gvy = 0.f, gvz = 0.f, gvw = 0.f;
    int   tcur = 0;
    bool  pend = false;

    const int NHW = 7 + 2 * (TSEQ - 1) + 2;   // L3's last TW at hw=518 -> 519

    for (int hw = 0; hw < NHW; ++hw) {
        const bool rmPhase = ((hw & 1) == (isB ? 1 : 0));

        if (rmPhase) {
            const int t = (hw - rmStart) >> 1;
            if (hw >= rmStart && t < TSEQ) {
                const int sv = t & 3;          // slot of h_{L-1}(t)
                const int sh = (t - 1) & 3;    // slot of h_L(t-1)

                // ---- R: input fragments ----
                f16x8 vf0, vf1;
                if (L == 0) {
                    vf0 = cvt8(R0, R1);            // x(t)
                    vf1 = cvt8(R2, R3);
                    if (t + 1 < TSEQ && n < 2) {   // prefetch x(t+1)
                        const float* p = xbase + (size_t)(t + 1) * 64;
                        R0 = *(const float4*)(p);      R1 = *(const float4*)(p + 4);
                        R2 = *(const float4*)(p + 32); R3 = *(const float4*)(p + 36);
                    }
                } else {
                    const _Float16* vp = &Hb[sv][L - 1][n & 1][0];
                    vf0 = *(const f16x8*)(vp + q * 8);
                    vf1 = *(const f16x8*)(vp + 32 + q * 8);
                }
                const _Float16* hp = &Hb[sh][L][n & 1][0];
                f16x8 hf0 = *(const f16x8*)(hp + q * 8);
                f16x8 hf1 = *(const f16x8*)(hp + 32 + q * 8);

                const f32x4 z4 = {0.f, 0.f, 0.f, 0.f};

                // ---- M: 32 MFMA + direct C[g] f32x4 scatter (8 lanes write) ----
#pragma unroll
                for (int j = 0; j < 2; ++j) {
                    f32x4 C[4];
#pragma unroll
                    for (int g = 0; g < 4; ++g) {
                        f32x4 c;
                        c = __builtin_amdgcn_mfma_f32_16x16x32_f16(Ahh[g][j][0], hf0, z4, 0, 0, 0);
                        c = __builtin_amdgcn_mfma_f32_16x16x32_f16(Ahh[g][j][1], hf1, c,  0, 0, 0);
                        c = __builtin_amdgcn_mfma_f32_16x16x32_f16(Aih[g][j][0], vf0, c,  0, 0, 0);
                        C[g] = __builtin_amdgcn_mfma_f32_16x16x32_f16(Aih[g][j][1], vf1, c, 0, 0, 0);
                    }
                    if (n < 2) {
#pragma unroll
                        for (int g = 0; g < 4; ++g)
                            *(f32x4*)&Gs[wo + j * 64 + g * 16] = C[g];
                    }
                }

                // ---- same-wave gather issue: 4 gates for this lane's (unit,el) ----
                gvx = Gs[ro];
                gvy = Gs[ro + 16];
                gvz = Gs[ro + 32];
                gvw = Gs[ro + 48];
                tcur = t;
                pend = true;
            }
        } else if (pend) {
            // ---- T: transcendentals + cell update ----
            float gi = sigm(gvx + be.x);
            float gf = sigm(gvy + be.y);
            float gg = tanh_fast(gvz + be.z);
            float go = sigm(gvw + be.w);
            cst = gf * cst + gi * gg;
            float h = go * tanh_fast(cst);

            // ---- W: publish h (and L3 output) ----
            if (L == 3) outp[(size_t)tcur * 64] = h;
            Hb[tcur & 3][L][el][unit] = (_Float16)h;
            pend = false;
        }

        // ---- raw barrier: drain LDS only; global loads/stores stay in flight ----
        __builtin_amdgcn_sched_barrier(0);
        asm volatile("s_waitcnt lgkmcnt(0)" ::: "memory");
        __builtin_amdgcn_s_barrier();
        __builtin_amdgcn_sched_barrier(0);
    }
}

extern "C" void kernel_launch(void* const* d_in, const int* in_sizes, int n_in,
                              void* d_out, int out_size, void* d_ws, size_t ws_size,
                              hipStream_t stream) {
    const float* x = (const float*)d_in[0];
    float* out = (float*)d_out;

    lstm_fused10<<<256, 512, 0, stream>>>(
        x, out,
        (const float*)d_in[1],  (const float*)d_in[2],
        (const float*)d_in[3],  (const float*)d_in[4],
        (const float*)d_in[5],  (const float*)d_in[6],
        (const float*)d_in[7],  (const float*)d_in[8],
        (const float*)d_in[9],  (const float*)d_in[10],
        (const float*)d_in[11], (const float*)d_in[12],
        (const float*)d_in[13], (const float*)d_in[14],
        (const float*)d_in[15], (const float*)d_in[16]);
}

// Round 9
// 383.521 us; speedup vs baseline: 1.4411x; 1.4411x over previous
//
#include <hip/hip_runtime.h>

// LSTM autoencoder: 4 layers 64->64, B=512, T=256 — fused, single barrier/tick.
//
// 256 blocks x 512 threads (1 block/CU). Block = 2 batch elements x 4 layers.
// Wave w = (layer L = w>>1, unit-half mh = w&1) owns units [mh*32, mh*32+32).
//
// ROUND-8 SYNTHESIS (measured ladder):
//   fused6 (347us): Gs LDS round-trip = dominant stall (43% neither-pipe-busy,
//     2.1e7 bank conflicts); epilogue spread 64 lanes (VALU 24%).
//   fused7 (372us): transposed MFMA removed Gs (stalls -> 16%, conflicts 0)
//     but concentrated epilogue into 16 lanes (VALU 53%).
// This kernel takes both wins: TRANSPOSED MFMA (C' = act * W^T; lane n holds
// all 4 gates of its units in registers) + ds_bpermute REDISTRIBUTE
// (16 bpermute + 8 cndmask, reg->reg, no LDS buffer, no conflicts) to spread
// the epilogue back to 1 cell/lane across all 64 lanes.
//   dst lane d = b*32 + s*16 + n pulls Cgs[s][g][b] from src lane d&15
//   (s = q&1, b = q>>1 on the destination side; el/unit mapping = fused6's).
// Per tick: frag reads -> 32 MFMA (8 indep chains of 4) -> 16 bpermute ->
// 1-cell epilogue -> h to Hb parity buffer; raw s_barrier with lgkmcnt(0)-only
// drain (vmcnt stays in flight: x prefetch + out stores).
// L0's x is prefetched one tick ahead into statically-named f32 regs.

typedef _Float16 f16x8 __attribute__((ext_vector_type(8)));
typedef float    f32x4 __attribute__((ext_vector_type(4)));

#define TSEQ 256

__device__ __forceinline__ float fast_rcp(float x) { return __builtin_amdgcn_rcpf(x); }
__device__ __forceinline__ float sigm(float x) { return fast_rcp(1.0f + __expf(-x)); }
__device__ __forceinline__ float tanh_fast(float x) {
    return 2.0f * fast_rcp(1.0f + __expf(-2.0f * x)) - 1.0f;
}
__device__ __forceinline__ f16x8 cvt8(float4 a, float4 b) {
    f16x8 f;
    f[0] = (_Float16)a.x; f[1] = (_Float16)a.y; f[2] = (_Float16)a.z; f[3] = (_Float16)a.w;
    f[4] = (_Float16)b.x; f[5] = (_Float16)b.y; f[6] = (_Float16)b.z; f[7] = (_Float16)b.w;
    return f;
}
__device__ __forceinline__ float bperm(int addr, float v) {
    return __int_as_float(__builtin_amdgcn_ds_bpermute(addr, __float_as_int(v)));
}

__global__ __launch_bounds__(512, 2)
void lstm_fused11(const float* __restrict__ x,     // [512, 256, 64]
                  float* __restrict__ out,         // [512, 256, 64]
                  const float* __restrict__ Wih0, const float* __restrict__ Whh0,
                  const float* __restrict__ bi0,  const float* __restrict__ bh0,
                  const float* __restrict__ Wih1, const float* __restrict__ Whh1,
                  const float* __restrict__ bi1,  const float* __restrict__ bh1,
                  const float* __restrict__ Wih2, const float* __restrict__ Whh2,
                  const float* __restrict__ bi2,  const float* __restrict__ bh2,
                  const float* __restrict__ Wih3, const float* __restrict__ Whh3,
                  const float* __restrict__ bi3,  const float* __restrict__ bh3)
{
    __shared__ _Float16 Hb[2][4][2][64];     // 2 KB: parity, layer, el(batch), unit

    const int tid  = threadIdx.x;
    const int wave = tid >> 6;
    const int lane = tid & 63;
    const int L    = wave >> 1;     // layer 0..3
    const int mh   = wave & 1;      // unit-half: units [mh*32, mh*32+32)
    const int q    = lane >> 4;     // k-quad (MFMA); also (s,b) selector (epilogue)
    const int n    = lane & 15;     // B cols = weight-rows-within-tile; A rows = batch (n&1)
    const int b0   = blockIdx.x * 2;

    const float* Wih = (L == 0) ? Wih0 : (L == 1) ? Wih1 : (L == 2) ? Wih2 : Wih3;
    const float* Whh = (L == 0) ? Whh0 : (L == 1) ? Whh1 : (L == 2) ? Whh2 : Whh3;
    const float* bi  = (L == 0) ? bi0  : (L == 1) ? bi1  : (L == 2) ? bi2  : bi3;
    const float* bh  = (L == 0) ? bh0  : (L == 1) ? bh1  : (L == 2) ? bh2  : bh3;

    // ---- persistent W fragments, used as the MFMA *B* operand ----
    // B[k=q*8+kk][col=n] = W[row][c*32+q*8+kk], row = g*64+mh*32+s*16+n.
    f16x8 Bih[4][2][2], Bhh[4][2][2];
#pragma unroll
    for (int g = 0; g < 4; ++g) {
#pragma unroll
        for (int s = 0; s < 2; ++s) {
            const int row = g * 64 + mh * 32 + s * 16 + n;
#pragma unroll
            for (int c = 0; c < 2; ++c) {
                const float* pi = Wih + row * 64 + c * 32 + q * 8;
                const float* ph = Whh + row * 64 + c * 32 + q * 8;
                f16x8 fi, fh;
#pragma unroll
                for (int k = 0; k < 8; ++k) { fi[k] = (_Float16)pi[k]; fh[k] = (_Float16)ph[k]; }
                Bih[g][s][c] = fi;
                Bhh[g][s][c] = fh;
            }
        }
    }

    // ---- epilogue identity (same lane map as fused6):
    //      el = lane>>5 (batch), unit = mh*32 + (lane&31) ----
    const int eu = lane & 31;
    const int el = lane >> 5;
    const int unit = mh * 32 + eu;
    float4 be;
    be.x = bi[unit]       + bh[unit];
    be.y = bi[64 + unit]  + bh[64 + unit];
    be.z = bi[128 + unit] + bh[128 + unit];
    be.w = bi[192 + unit] + bh[192 + unit];
    float cst = 0.0f;
    float* outp = out + ((size_t)(b0 + el) * TSEQ) * 64 + unit;   // L==3 only

    const int baddr = n * 4;        // bpermute: pull from source lane (lane&15)

    // ---- zero h state (both parities): 2048 B = 512 ints ----
    ((int*)Hb)[tid] = 0;

    // ---- L0 x prefetch: raw f32 one tick ahead (lanes n<2 only; rest zero) ----
    const float* xbase = x + ((size_t)(b0 + (n & 1)) * TSEQ) * 64 + q * 8;
    float4 R0, R1, R2, R3;
    R0 = R1 = R2 = R3 = make_float4(0.f, 0.f, 0.f, 0.f);
    if (L == 0 && n < 2) {
        R0 = *(const float4*)(xbase);      R1 = *(const float4*)(xbase + 4);
        R2 = *(const float4*)(xbase + 32); R3 = *(const float4*)(xbase + 36);
    }

    __syncthreads();

    for (int tau = 0; tau < TSEQ + 3; ++tau) {
        const int  t   = tau - L;
        const bool act = (unsigned)t < TSEQ;   // wave-uniform
        const int  pr  = (tau + 1) & 1;
        const int  pw  = tau & 1;

        if (act) {
            // ---- A-operand fragments (rows = batch via n&1; rows 2..15 dup/zero) ----
            f16x8 vf0, vf1;
            if (L == 0) {
                vf0 = cvt8(R0, R1);            // x(t)
                vf1 = cvt8(R2, R3);
                if (t + 1 < TSEQ && n < 2) {   // prefetch x(t+1)
                    const float* p = xbase + (size_t)(t + 1) * 64;
                    R0 = *(const float4*)(p);      R1 = *(const float4*)(p + 4);
                    R2 = *(const float4*)(p + 32); R3 = *(const float4*)(p + 36);
                }
            } else {
                const _Float16* vp = &Hb[pr][L - 1][n & 1][0];
                vf0 = *(const f16x8*)(vp + q * 8);
                vf1 = *(const f16x8*)(vp + 32 + q * 8);
            }
            const _Float16* hp = &Hb[pr][L][n & 1][0];
            f16x8 hf0 = *(const f16x8*)(hp + q * 8);
            f16x8 hf1 = *(const f16x8*)(hp + 32 + q * 8);

            const f32x4 z4 = {0.f, 0.f, 0.f, 0.f};

            // ---- 32 MFMA, transposed: C'[batch][unit] = act * W^T ----
            f32x4 Cgs[2][4];                   // [s][g]; 8 independent chains of 4
#pragma unroll
            for (int s = 0; s < 2; ++s) {
#pragma unroll
                for (int g = 0; g < 4; ++g) {
                    f32x4 c;
                    c = __builtin_amdgcn_mfma_f32_16x16x32_f16(hf0, Bhh[g][s][0], z4, 0, 0, 0);
                    c = __builtin_amdgcn_mfma_f32_16x16x32_f16(hf1, Bhh[g][s][1], c,  0, 0, 0);
                    c = __builtin_amdgcn_mfma_f32_16x16x32_f16(vf0, Bih[g][s][0], c,  0, 0, 0);
                    Cgs[s][g] = __builtin_amdgcn_mfma_f32_16x16x32_f16(vf1, Bih[g][s][1], c, 0, 0, 0);
                }
            }

            // ---- reg->reg redistribute: lane d=b*32+s*16+n takes Cgs[s][g][b]
            //      from lane d&15 (16 bpermute + 8 cndmask, no LDS buffer) ----
            float gv[4];
#pragma unroll
            for (int g = 0; g < 4; ++g) {
                float v00 = bperm(baddr, Cgs[0][g][0]);   // s=0, b=0
                float v10 = bperm(baddr, Cgs[1][g][0]);   // s=1, b=0
                float v01 = bperm(baddr, Cgs[0][g][1]);   // s=0, b=1
                float v11 = bperm(baddr, Cgs[1][g][1]);   // s=1, b=1
                float lo = (q & 1) ? v10 : v00;           // select s
                float hi = (q & 1) ? v11 : v01;
                gv[g] = (q & 2) ? hi : lo;                // select b
            }

            // ---- 1-cell epilogue (64-lane spread, same map as fused6) ----
            float gi = sigm(gv[0] + be.x);
            float gf = sigm(gv[1] + be.y);
            float gg = tanh_fast(gv[2] + be.z);
            float go = sigm(gv[3] + be.w);
            cst = gf * cst + gi * gg;
            float h = go * tanh_fast(cst);

            if (L == 3) outp[(size_t)t * 64] = h;
            Hb[pw][L][el][unit] = (_Float16)h;
        }
        // ---- raw barrier: drain LDS only; global loads/stores stay in flight ----
        __builtin_amdgcn_sched_barrier(0);
        asm volatile("s_waitcnt lgkmcnt(0)" ::: "memory");
        __builtin_amdgcn_s_barrier();
        __builtin_amdgcn_sched_barrier(0);
    }
}

extern "C" void kernel_launch(void* const* d_in, const int* in_sizes, int n_in,
                              void* d_out, int out_size, void* d_ws, size_t ws_size,
                              hipStream_t stream) {
    const float* x = (const float*)d_in[0];
    float* out = (float*)d_out;

    lstm_fused11<<<256, 512, 0, stream>>>(
        x, out,
        (const float*)d_in[1],  (const float*)d_in[2],
        (const float*)d_in[3],  (const float*)d_in[4],
        (const float*)d_in[5],  (const float*)d_in[6],
        (const float*)d_in[7],  (const float*)d_in[8],
        (const float*)d_in[9],  (const float*)d_in[10],
        (const float*)d_in[11], (const float*)d_in[12],
        (const float*)d_in[13], (const float*)d_in[14],
        (const float*)d_in[15], (const float*)d_in[16]);
}